// Round 1
// baseline (65.265 us; speedup 1.0000x reference)
//
#include <hip/hip_runtime.h>

// FRAP forward — fully fused single-workgroup kernel.
// Latency-bound: ~1.2M MACs total, serial layer chain, 8-float output.
// 1 block x 1024 threads; all activations in one 64KB LDS pool, regions
// aliased across phases (barriers between every producer/consumer).
//
// LDS map (floats):
//   early phases (aliased into big's region, all consumed before P8):
//     feat @0(112)  dh1 @128(2048)  dh2 @2176(256)  dem @2432(32)
//     vec @2464(64)  ch1 @2560(1024)  ch2 @3584(256)
//   conv phases:
//     big @0      : 56 x 256, XOR-swizzled [s][c] (conv h1 outs; later h3 @0..447)
//     mid @14336  : 32 x 56  [o][s]              (conv h2 outs)
//     dp  @16128  : 8 x 4                          (survives into P8)
//     Hd  @16160  : 2 x 56                         (survives into P11)
// Swizzle: element (s,c) lives at big[s*256 + ((c>>2)^(s&7))*4 + (c&3)]
//  -> writes (consecutive o per lane) conflict-free, float4 reads bank-uniform.

#define DEV __device__ __forceinline__

DEV float dot4(float4 a, float4 b) {
    return a.x * b.x + a.y * b.y + a.z * b.z + a.w * b.w;
}

// conv h2 stage: in big (swizzled [s][256]) -> relu(w2(32x256) @ .) -> mid[o*56+s]
// 224 threads, 8 output channels per thread: 1 ds_read_b128 feeds 32 FMAs.
DEV void conv_h2_phase(const float* __restrict__ big, const float* __restrict__ w2,
                       const float* __restrict__ b2, float* __restrict__ mid, int t)
{
    if (t < 224) {
        int s = t % 56, og = t / 56;            // og 0..3 -> 8 channels each
        const float4* hrow = (const float4*)(big + (s << 8));
        int sw = s & 7;
        float acc[8];
#pragma unroll
        for (int q = 0; q < 8; ++q) acc[q] = b2[og * 8 + q];
#pragma unroll 4
        for (int g = 0; g < 64; ++g) {
            float4 v = hrow[g ^ sw];
#pragma unroll
            for (int q = 0; q < 8; ++q) {
                float4 w = ((const float4*)(w2 + (og * 8 + q) * 256))[g];
                acc[q] += dot4(v, w);
            }
        }
#pragma unroll
        for (int q = 0; q < 8; ++q)
            mid[(og * 8 + q) * 56 + s] = fmaxf(acc[q], 0.0f);
    }
}

__global__ __launch_bounds__(1024, 1) void frap_kernel(
    const float* __restrict__ waiting, const float* __restrict__ phase,
    const float* __restrict__ wtime_mu, const float* __restrict__ wtime_sigma,
    const float* __restrict__ wtime_max,
    const float* __restrict__ i_pos, const float* __restrict__ j_pos,
    const float* __restrict__ d_w1, const float* __restrict__ d_b1,
    const float* __restrict__ d_w2, const float* __restrict__ d_b2,
    const float* __restrict__ d_w3, const float* __restrict__ d_b3,
    const float* __restrict__ c_w1, const float* __restrict__ c_b1,
    const float* __restrict__ c_w2, const float* __restrict__ c_b2,
    const float* __restrict__ c_w3, const float* __restrict__ c_b3,
    const float* __restrict__ dD_w1, const float* __restrict__ dD_b1,
    const float* __restrict__ dD_w2, const float* __restrict__ dD_b2,
    const float* __restrict__ dD_w3, const float* __restrict__ dD_b3,
    const float* __restrict__ cC_w1, const float* __restrict__ cC_b1,
    const float* __restrict__ cC_w2, const float* __restrict__ cC_b2,
    const float* __restrict__ cC_w3, const float* __restrict__ cC_b3,
    const float* __restrict__ cC_w4, const float* __restrict__ cC_b4,
    float* __restrict__ out)
{
    __shared__ __align__(16) float sm[16384];   // 64 KB
    const int t = threadIdx.x;

    float* feat = sm;          // 112
    float* dh1  = sm + 128;    // 2048
    float* dh2  = sm + 2176;   // 256
    float* dem  = sm + 2432;   // 32
    float* vec  = sm + 2464;   // 64
    float* ch1  = sm + 2560;   // 1024
    float* ch2  = sm + 3584;   // 256
    float* big  = sm;          // 14336 (swizzled [s][256])
    float* mid  = sm + 14336;  // 1792  [o][56]
    float* dp   = sm + 16128;  // 32
    float* Hd   = sm + 16160;  // 112
    float* h3   = sm;          // 448 (reuses big after P12)

    // ---- P0: feat (8 x 14) = [i, j, mu, sigma, max, wait, phase(8)]
    if (t < 112) {
        int l = t / 14, c = t - l * 14;
        float v;
        if      (c == 0) v = i_pos[0];
        else if (c == 1) v = j_pos[0];
        else if (c == 2) v = wtime_mu[l];
        else if (c == 3) v = wtime_sigma[l];
        else if (c == 4) v = wtime_max[l];
        else if (c == 5) v = waiting[l];
        else             v = phase[c - 6];
        feat[t] = v;
    }
    __syncthreads();

    // ---- P1: demand h1 = relu(feat(8x14) @ d_w1^T) -> dh1[l*256+o]
    for (int idx = t; idx < 2048; idx += 1024) {
        int l = idx >> 8, o = idx & 255;
        const float* w = d_w1 + o * 14;
        const float* f = feat + l * 14;
        float acc = d_b1[o];
#pragma unroll
        for (int c = 0; c < 14; ++c) acc = fmaf(f[c], w[c], acc);
        dh1[idx] = fmaxf(acc, 0.0f);
    }
    __syncthreads();

    // ---- P2: demand h2 (8x32), K=256
    if (t < 256) {
        int l = t >> 5, o = t & 31;
        const float4* w = (const float4*)(d_w2 + o * 256);
        const float4* h = (const float4*)(dh1 + l * 256);
        float acc = d_b2[o];
#pragma unroll 8
        for (int g = 0; g < 64; ++g) acc += dot4(h[g], w[g]);
        dh2[l * 32 + o] = fmaxf(acc, 0.0f);
    }
    __syncthreads();

    // ---- P3: demand out (8x4), K=32, no relu
    if (t < 32) {
        int l = t >> 2, o = t & 3;
        const float4* w = (const float4*)(d_w3 + o * 32);
        const float4* h = (const float4*)(dh2 + l * 32);
        float acc = d_b3[o];
#pragma unroll
        for (int g = 0; g < 8; ++g) acc += dot4(h[g], w[g]);
        dem[l * 4 + o] = acc;
    }
    __syncthreads();

    // ---- P4: vec (8x8) via phase pairs
    // PAIRS = {0,4},{1,5},{2,6},{3,7},{0,5},{1,4},{2,7},{3,6}
    if (t < 64) {
        int p = t >> 3, c = t & 7;
        int a0 = p & 3;
        int a1 = (p < 4) ? (4 + (p & 3)) : (4 + ((p & 3) ^ 1));
        int lane_sel = (c < 4) ? a0 : a1;
        vec[t] = dem[lane_sel * 4 + (c & 3)];
    }
    __syncthreads();

    // ---- P5: coupled h1 (8x128), K=8
    {
        int p = t >> 7, o = t & 127;
        const float4* w  = (const float4*)(c_w1 + o * 8);
        const float4* v4 = (const float4*)(vec + p * 8);
        float acc = c_b1[o] + dot4(v4[0], w[0]) + dot4(v4[1], w[1]);
        ch1[t] = fmaxf(acc, 0.0f);
    }
    __syncthreads();

    // ---- P6: coupled h2 (8x32), K=128
    if (t < 256) {
        int l = t >> 5, o = t & 31;
        const float4* w = (const float4*)(c_w2 + o * 128);
        const float4* h = (const float4*)(ch1 + l * 128);
        float acc = c_b2[o];
#pragma unroll 8
        for (int g = 0; g < 32; ++g) acc += dot4(h[g], w[g]);
        ch2[l * 32 + o] = fmaxf(acc, 0.0f);
    }
    __syncthreads();

    // ---- P7: dp (8x4), K=32, no relu -> TINY region (survives P8)
    if (t < 32) {
        int l = t >> 2, o = t & 3;
        const float4* w = (const float4*)(c_w3 + o * 32);
        const float4* h = (const float4*)(ch2 + l * 32);
        float acc = c_b3[o];
#pragma unroll
        for (int g = 0; g < 8; ++g) acc += dot4(h[g], w[g]);
        dp[l * 4 + o] = acc;
    }
    __syncthreads();

    // ---- P8: conv_D h1 (256 x 56): D built on the fly from dp
    // D[c][i][k] = dp[i][c] (c<4) | dp[j][c-4],  j = k + (k>=i)
    {
        const float4* dp4 = (const float4*)dp;
        for (int idx = t; idx < 14336; idx += 1024) {
            int s = idx >> 8, o = idx & 255;
            int i = s / 7, k = s - i * 7;
            int j = k + (k >= i ? 1 : 0);
            const float4* w = (const float4*)(dD_w1 + o * 8);
            float acc = dD_b1[o] + dot4(dp4[i], w[0]) + dot4(dp4[j], w[1]);
            big[(s << 8) + (o ^ ((s & 7) << 2))] = fmaxf(acc, 0.0f);
        }
    }
    __syncthreads();

    // ---- P9: conv_D h2 (32 x 56), K=256
    conv_h2_phase(big, dD_w2, dD_b2, mid, t);
    __syncthreads();

    // ---- P10: conv_D h3 -> Hd (2 x 56), K=32, no relu
    if (t < 112) {
        int o = t / 56, s = t - o * 56;
        float acc = dD_b3[o];
#pragma unroll
        for (int c = 0; c < 32; ++c) acc = fmaf(mid[c * 56 + s], dD_w3[o * 32 + c], acc);
        Hd[o * 56 + s] = acc;
    }
    __syncthreads();

    // ---- P11: conv_C h1 (256 x 56): channel 2 of H_c is zero -> 2 taps
    for (int idx = t; idx < 14336; idx += 1024) {
        int s = idx >> 8, o = idx & 255;
        float acc = cC_b1[o] + Hd[s] * cC_w1[o * 3] + Hd[56 + s] * cC_w1[o * 3 + 1];
        big[(s << 8) + (o ^ ((s & 7) << 2))] = fmaxf(acc, 0.0f);
    }
    __syncthreads();

    // ---- P12: conv_C h2 (32 x 56), K=256
    conv_h2_phase(big, cC_w2, cC_b2, mid, t);
    __syncthreads();

    // ---- P13: conv_C h3 (8 x 56), K=32, relu -> h3 (reuses big region)
    if (t < 448) {
        int o = t / 56, s = t - o * 56;
        float acc = cC_b3[o];
#pragma unroll
        for (int c = 0; c < 32; ++c) acc = fmaf(mid[c * 56 + s], cC_w3[o * 32 + c], acc);
        h3[o * 56 + s] = fmaxf(acc, 0.0f);
    }
    __syncthreads();

    // ---- P14: final (1,7) conv: out[h] = sum_{c,w} cC_w4[c][w]*h3[c][h*7+w] + b4
    if (t < 64) {
        int h = t >> 3, c = t & 7;
        float p = 0.0f;
#pragma unroll
        for (int w = 0; w < 7; ++w)
            p = fmaf(cC_w4[c * 7 + w], h3[c * 56 + h * 7 + w], p);
#pragma unroll
        for (int off = 1; off < 8; off <<= 1) p += __shfl_xor(p, off);
        if (c == 0) out[h] = p + cC_b4[0];
    }
}

extern "C" void kernel_launch(void* const* d_in, const int* in_sizes, int n_in,
                              void* d_out, int out_size, void* d_ws, size_t ws_size,
                              hipStream_t stream) {
    (void)in_sizes; (void)n_in; (void)d_ws; (void)ws_size; (void)out_size;
    const float* a[33];
    for (int i = 0; i < 33; ++i) a[i] = (const float*)d_in[i];
    frap_kernel<<<dim3(1), dim3(1024), 0, stream>>>(
        a[0], a[1], a[2], a[3], a[4], a[5], a[6],
        a[7], a[8], a[9], a[10], a[11], a[12],
        a[13], a[14], a[15], a[16], a[17], a[18],
        a[19], a[20], a[21], a[22], a[23], a[24],
        a[25], a[26], a[27], a[28], a[29], a[30], a[31], a[32],
        (float*)d_out);
}

// Round 2
// 52.923 us; speedup vs baseline: 1.2332x; 1.2332x over previous
//
#include <hip/hip_runtime.h>

// FRAP forward — fully fused single-workgroup kernel (round 2).
// R1 diagnosis: FETCH_SIZE ~86KB/dispatch = weight set re-fetched from HBM
// every replay, as scattered demand misses inside a serial phase chain with
// few active waves -> ~80% stall. Fix: (a) parallel weight-warm prologue
// (all 1024 threads, coalesced float4, one burst); (b) heavy conv phases
// widened 224x8ch -> 448x4ch for 2x wave count.
//
// LDS map (floats):
//   early phases (aliased into big's region, all consumed before P8):
//     feat @0(112)  dh1 @128(2048)  dh2 @2176(256)  dem @2432(32)
//     vec @2464(64)  ch1 @2560(1024)  ch2 @3584(256)
//   conv phases:
//     big @0      : 56 x 256, XOR-swizzled [s][c] (conv h1 outs; later h3 @0..447)
//     mid @14336  : 32 x 56  [o][s]              (conv h2 outs)
//     dp  @16128  : 8 x 4                          (survives into P8)
//     Hd  @16160  : 2 x 56                         (survives into P11)
// Swizzle: element (s,c) lives at big[s*256 + ((c>>2)^(s&7))*4 + (c&3)]

#define DEV __device__ __forceinline__

DEV float dot4(float4 a, float4 b) {
    return a.x * b.x + a.y * b.y + a.z * b.z + a.w * b.w;
}

// Coalesced cache-warm of one weight array (n4 = count of float4s).
DEV float warm_arr(const float* __restrict__ p, int n4, int t, float sink) {
    const float4* p4 = (const float4*)p;
    for (int i = t; i < n4; i += 1024) {
        float4 v = p4[i];
        sink += v.x + v.y + v.z + v.w;
    }
    return sink;
}

// conv h2 stage: big (swizzled [s][256]) -> relu(w2(32x256) @ .) -> mid[o*56+s]
// 448 threads (7 waves), 4 output channels per thread.
DEV void conv_h2_phase(const float* __restrict__ big, const float* __restrict__ w2,
                       const float* __restrict__ b2, float* __restrict__ mid, int t)
{
    if (t < 448) {
        int s = t % 56, og = t / 56;            // og 0..7 -> 4 channels each
        const float4* hrow = (const float4*)(big + (s << 8));
        int sw = s & 7;
        float acc[4];
#pragma unroll
        for (int q = 0; q < 4; ++q) acc[q] = b2[og * 4 + q];
#pragma unroll 4
        for (int g = 0; g < 64; ++g) {
            float4 v = hrow[g ^ sw];
#pragma unroll
            for (int q = 0; q < 4; ++q) {
                float4 w = ((const float4*)(w2 + (og * 4 + q) * 256))[g];
                acc[q] += dot4(v, w);
            }
        }
#pragma unroll
        for (int q = 0; q < 4; ++q)
            mid[(og * 4 + q) * 56 + s] = fmaxf(acc[q], 0.0f);
    }
}

__global__ __launch_bounds__(1024, 1) void frap_kernel(
    const float* __restrict__ waiting, const float* __restrict__ phase,
    const float* __restrict__ wtime_mu, const float* __restrict__ wtime_sigma,
    const float* __restrict__ wtime_max,
    const float* __restrict__ i_pos, const float* __restrict__ j_pos,
    const float* __restrict__ d_w1, const float* __restrict__ d_b1,
    const float* __restrict__ d_w2, const float* __restrict__ d_b2,
    const float* __restrict__ d_w3, const float* __restrict__ d_b3,
    const float* __restrict__ c_w1, const float* __restrict__ c_b1,
    const float* __restrict__ c_w2, const float* __restrict__ c_b2,
    const float* __restrict__ c_w3, const float* __restrict__ c_b3,
    const float* __restrict__ dD_w1, const float* __restrict__ dD_b1,
    const float* __restrict__ dD_w2, const float* __restrict__ dD_b2,
    const float* __restrict__ dD_w3, const float* __restrict__ dD_b3,
    const float* __restrict__ cC_w1, const float* __restrict__ cC_b1,
    const float* __restrict__ cC_w2, const float* __restrict__ cC_b2,
    const float* __restrict__ cC_w3, const float* __restrict__ cC_b3,
    const float* __restrict__ cC_w4, const float* __restrict__ cC_b4,
    float* __restrict__ out)
{
    __shared__ __align__(16) float sm[16384];   // 64 KB
    const int t = threadIdx.x;

    float* feat = sm;          // 112
    float* dh1  = sm + 128;    // 2048
    float* dh2  = sm + 2176;   // 256
    float* dem  = sm + 2432;   // 32
    float* vec  = sm + 2464;   // 64
    float* ch1  = sm + 2560;   // 1024
    float* ch2  = sm + 3584;   // 256
    float* big  = sm;          // 14336 (swizzled [s][256])
    float* mid  = sm + 14336;  // 1792  [o][56]
    float* dp   = sm + 16128;  // 32
    float* Hd   = sm + 16160;  // 112
    float* h3   = sm;          // 448 (reuses big after P12)

    // ---- Warm: one parallel coalesced burst over the whole weight set.
    // Converts ~1500 scattered serial L2/HBM misses into one overlapped burst.
    {
        float snk = 0.0f;
        snk = warm_arr(d_w1,  896, t, snk);   // 256x14
        snk = warm_arr(d_b1,   64, t, snk);
        snk = warm_arr(d_w2, 2048, t, snk);   // 32x256
        snk = warm_arr(d_b2,    8, t, snk);
        snk = warm_arr(d_w3,   32, t, snk);
        snk = warm_arr(d_b3,    1, t, snk);
        snk = warm_arr(c_w1,  256, t, snk);   // 128x8
        snk = warm_arr(c_b1,   32, t, snk);
        snk = warm_arr(c_w2, 1024, t, snk);   // 32x128
        snk = warm_arr(c_b2,    8, t, snk);
        snk = warm_arr(c_w3,   32, t, snk);
        snk = warm_arr(c_b3,    1, t, snk);
        snk = warm_arr(dD_w1, 512, t, snk);   // 256x8
        snk = warm_arr(dD_b1,  64, t, snk);
        snk = warm_arr(dD_w2, 2048, t, snk);  // 32x256
        snk = warm_arr(dD_b2,   8, t, snk);
        snk = warm_arr(dD_w3,  16, t, snk);
        snk = warm_arr(cC_w1, 192, t, snk);   // 256x3
        snk = warm_arr(cC_b1,  64, t, snk);
        snk = warm_arr(cC_w2, 2048, t, snk);  // 32x256
        snk = warm_arr(cC_b2,   8, t, snk);
        snk = warm_arr(cC_w3,  64, t, snk);
        snk = warm_arr(cC_b3,   2, t, snk);
        snk = warm_arr(cC_w4,  14, t, snk);
        asm volatile("" :: "v"(snk));         // keep the burst alive, no DCE
    }

    // ---- P0: feat (8 x 14) = [i, j, mu, sigma, max, wait, phase(8)]
    if (t < 112) {
        int l = t / 14, c = t - l * 14;
        float v;
        if      (c == 0) v = i_pos[0];
        else if (c == 1) v = j_pos[0];
        else if (c == 2) v = wtime_mu[l];
        else if (c == 3) v = wtime_sigma[l];
        else if (c == 4) v = wtime_max[l];
        else if (c == 5) v = waiting[l];
        else             v = phase[c - 6];
        feat[t] = v;
    }
    __syncthreads();

    // ---- P1: demand h1 = relu(feat(8x14) @ d_w1^T) -> dh1[l*256+o]
    for (int idx = t; idx < 2048; idx += 1024) {
        int l = idx >> 8, o = idx & 255;
        const float* w = d_w1 + o * 14;
        const float* f = feat + l * 14;
        float acc = d_b1[o];
#pragma unroll
        for (int c = 0; c < 14; ++c) acc = fmaf(f[c], w[c], acc);
        dh1[idx] = fmaxf(acc, 0.0f);
    }
    __syncthreads();

    // ---- P2: demand h2 (8x32), K=256
    if (t < 256) {
        int l = t >> 5, o = t & 31;
        const float4* w = (const float4*)(d_w2 + o * 256);
        const float4* h = (const float4*)(dh1 + l * 256);
        float acc = d_b2[o];
#pragma unroll 8
        for (int g = 0; g < 64; ++g) acc += dot4(h[g], w[g]);
        dh2[l * 32 + o] = fmaxf(acc, 0.0f);
    }
    __syncthreads();

    // ---- P3: demand out (8x4), K=32, no relu
    if (t < 32) {
        int l = t >> 2, o = t & 3;
        const float4* w = (const float4*)(d_w3 + o * 32);
        const float4* h = (const float4*)(dh2 + l * 32);
        float acc = d_b3[o];
#pragma unroll
        for (int g = 0; g < 8; ++g) acc += dot4(h[g], w[g]);
        dem[l * 4 + o] = acc;
    }
    __syncthreads();

    // ---- P4: vec (8x8) via phase pairs
    // PAIRS = {0,4},{1,5},{2,6},{3,7},{0,5},{1,4},{2,7},{3,6}
    if (t < 64) {
        int p = t >> 3, c = t & 7;
        int a0 = p & 3;
        int a1 = (p < 4) ? (4 + (p & 3)) : (4 + ((p & 3) ^ 1));
        int lane_sel = (c < 4) ? a0 : a1;
        vec[t] = dem[lane_sel * 4 + (c & 3)];
    }
    __syncthreads();

    // ---- P5: coupled h1 (8x128), K=8
    {
        int p = t >> 7, o = t & 127;
        const float4* w  = (const float4*)(c_w1 + o * 8);
        const float4* v4 = (const float4*)(vec + p * 8);
        float acc = c_b1[o] + dot4(v4[0], w[0]) + dot4(v4[1], w[1]);
        ch1[t] = fmaxf(acc, 0.0f);
    }
    __syncthreads();

    // ---- P6: coupled h2 (8x32), K=128
    if (t < 256) {
        int l = t >> 5, o = t & 31;
        const float4* w = (const float4*)(c_w2 + o * 128);
        const float4* h = (const float4*)(ch1 + l * 128);
        float acc = c_b2[o];
#pragma unroll 8
        for (int g = 0; g < 32; ++g) acc += dot4(h[g], w[g]);
        ch2[l * 32 + o] = fmaxf(acc, 0.0f);
    }
    __syncthreads();

    // ---- P7: dp (8x4), K=32, no relu -> TINY region (survives P8)
    if (t < 32) {
        int l = t >> 2, o = t & 3;
        const float4* w = (const float4*)(c_w3 + o * 32);
        const float4* h = (const float4*)(ch2 + l * 32);
        float acc = c_b3[o];
#pragma unroll
        for (int g = 0; g < 8; ++g) acc += dot4(h[g], w[g]);
        dp[l * 4 + o] = acc;
    }
    __syncthreads();

    // ---- P8: conv_D h1 (256 x 56): D built on the fly from dp
    // D[c][i][k] = dp[i][c] (c<4) | dp[j][c-4],  j = k + (k>=i)
    {
        const float4* dp4 = (const float4*)dp;
        for (int idx = t; idx < 14336; idx += 1024) {
            int s = idx >> 8, o = idx & 255;
            int i = s / 7, k = s - i * 7;
            int j = k + (k >= i ? 1 : 0);
            const float4* w = (const float4*)(dD_w1 + o * 8);
            float acc = dD_b1[o] + dot4(dp4[i], w[0]) + dot4(dp4[j], w[1]);
            big[(s << 8) + (o ^ ((s & 7) << 2))] = fmaxf(acc, 0.0f);
        }
    }
    __syncthreads();

    // ---- P9: conv_D h2 (32 x 56), K=256
    conv_h2_phase(big, dD_w2, dD_b2, mid, t);
    __syncthreads();

    // ---- P10: conv_D h3 -> Hd (2 x 56), K=32, no relu
    if (t < 112) {
        int o = t / 56, s = t - o * 56;
        float acc = dD_b3[o];
#pragma unroll
        for (int c = 0; c < 32; ++c) acc = fmaf(mid[c * 56 + s], dD_w3[o * 32 + c], acc);
        Hd[o * 56 + s] = acc;
    }
    __syncthreads();

    // ---- P11: conv_C h1 (256 x 56): channel 2 of H_c is zero -> 2 taps
    for (int idx = t; idx < 14336; idx += 1024) {
        int s = idx >> 8, o = idx & 255;
        float acc = cC_b1[o] + Hd[s] * cC_w1[o * 3] + Hd[56 + s] * cC_w1[o * 3 + 1];
        big[(s << 8) + (o ^ ((s & 7) << 2))] = fmaxf(acc, 0.0f);
    }
    __syncthreads();

    // ---- P12: conv_C h2 (32 x 56), K=256
    conv_h2_phase(big, cC_w2, cC_b2, mid, t);
    __syncthreads();

    // ---- P13: conv_C h3 (8 x 56), K=32, relu -> h3 (reuses big region)
    if (t < 448) {
        int o = t / 56, s = t - o * 56;
        float acc = cC_b3[o];
#pragma unroll
        for (int c = 0; c < 32; ++c) acc = fmaf(mid[c * 56 + s], cC_w3[o * 32 + c], acc);
        h3[o * 56 + s] = fmaxf(acc, 0.0f);
    }
    __syncthreads();

    // ---- P14: final (1,7) conv: out[h] = sum_{c,w} cC_w4[c][w]*h3[c][h*7+w] + b4
    if (t < 64) {
        int h = t >> 3, c = t & 7;
        float p = 0.0f;
#pragma unroll
        for (int w = 0; w < 7; ++w)
            p = fmaf(cC_w4[c * 7 + w], h3[c * 56 + h * 7 + w], p);
#pragma unroll
        for (int off = 1; off < 8; off <<= 1) p += __shfl_xor(p, off);
        if (c == 0) out[h] = p + cC_b4[0];
    }
}

extern "C" void kernel_launch(void* const* d_in, const int* in_sizes, int n_in,
                              void* d_out, int out_size, void* d_ws, size_t ws_size,
                              hipStream_t stream) {
    (void)in_sizes; (void)n_in; (void)d_ws; (void)ws_size; (void)out_size;
    const float* a[33];
    for (int i = 0; i < 33; ++i) a[i] = (const float*)d_in[i];
    frap_kernel<<<dim3(1), dim3(1024), 0, stream>>>(
        a[0], a[1], a[2], a[3], a[4], a[5], a[6],
        a[7], a[8], a[9], a[10], a[11], a[12],
        a[13], a[14], a[15], a[16], a[17], a[18],
        a[19], a[20], a[21], a[22], a[23], a[24],
        a[25], a[26], a[27], a[28], a[29], a[30], a[31], a[32],
        (float*)d_out);
}